// Round 10
// baseline (177.636 us; speedup 1.0000x reference)
//
#include <hip/hip_runtime.h>
#include <hip/hip_bf16.h>

#define BDIM 8
#define LDIM 128
#define TDIM 64
#define NFEAT 1024
#define HNUM 16
#define DH 64

#define GM 4096
#define GN 1024
#define GK 1024

typedef __attribute__((ext_vector_type(8))) short short8;
typedef __attribute__((ext_vector_type(4))) float f32x4;

// round-to-nearest-even f32 -> bf16 bits
__device__ __forceinline__ unsigned short f2bf(float x) {
  union { float f; unsigned u; } v; v.f = x;
  unsigned r = v.u + 0x7fffu + ((v.u >> 16) & 1u);
  return (unsigned short)(r >> 16);
}

// ---------------------------------------------------------------------------
// Kernel 1 (R9-proven body, verbatim): per block bl=(b1,l):
//   A: km = mean_t kv[bl] (LDS only)
//   B: kw[h][dd]  = sum_d Wk[dd][d]*km[h*64+d]
//   C: wqkw[h][i] = sum_dd Wq[dd][i]*kw[h][dd]; bqkw[h] = sum_dd bq[dd]*kw[h][dd]
//   D: score[h,b2] direct per-thread dots
//   E: weff row f=bl
// Scores layout: [b1][h][b2][l] (contiguous in l).
// ---------------------------------------------------------------------------
__global__ __launch_bounds__(256) void mean_score_weff_kernel(
    const float* __restrict__ kv, const float* __restrict__ q,
    const float* __restrict__ Wq, const float* __restrict__ bq,
    const float* __restrict__ Wk, const float* __restrict__ Wo,
    const float* __restrict__ Wv, const float* __restrict__ bv,
    const float* __restrict__ bo, float* __restrict__ scores,
    unsigned short* __restrict__ Weff, float* __restrict__ beff) {
  __shared__ float km_s[NFEAT];
  __shared__ float Wk_s[DH * 67];
  __shared__ float kw_s[HNUM * DH];
  __shared__ float wqkw_s[HNUM * 66];
  __shared__ float bqkw_s[HNUM];
  __shared__ float worow[NFEAT];
  __shared__ float red[256];
  const int bl = blockIdx.x;  // b1*128 + l
  const int tid = threadIdx.x;
  const int b1 = bl >> 7, l = bl & 127;

  // ---- A: mean over t of kv[bl, t, :] -> km_s ----
  {
    const float* src = kv + (size_t)bl * (TDIM * NFEAT) + tid * 4;
    float4 acc = make_float4(0.f, 0.f, 0.f, 0.f);
    for (int t0 = 0; t0 < TDIM; t0 += 8) {
      float4 v[8];
#pragma unroll
      for (int jj = 0; jj < 8; ++jj)
        v[jj] = *(const float4*)(src + (t0 + jj) * NFEAT);
#pragma unroll
      for (int jj = 0; jj < 8; ++jj) {
        acc.x += v[jj].x; acc.y += v[jj].y; acc.z += v[jj].z; acc.w += v[jj].w;
      }
    }
    const float s = 1.f / TDIM;
    *(float4*)(km_s + tid * 4) = make_float4(acc.x * s, acc.y * s, acc.z * s, acc.w * s);
  }
#pragma unroll
  for (int rep = 0; rep < 4; ++rep) {
    const int e4 = rep * 256 + tid;
    const int row = e4 >> 4, c4 = e4 & 15;
    const float4 v = *(const float4*)(Wk + row * DH + c4 * 4);
    float* dst = Wk_s + row * 67 + c4 * 4;
    dst[0] = v.x; dst[1] = v.y; dst[2] = v.z; dst[3] = v.w;
  }
  __syncthreads();
  // ---- B: kw ----
#pragma unroll
  for (int rep = 0; rep < 4; ++rep) {
    const int e = rep * 256 + tid;
    const int h = e >> 6, dd = e & 63;
    float acc = 0.f;
#pragma unroll 4
    for (int d = 0; d < DH; ++d) acc += Wk_s[dd * 67 + d] * km_s[h * 64 + d];
    kw_s[h * 64 + dd] = acc;
  }
  __syncthreads();
  // ---- C: wqkw + bqkw ----
#pragma unroll
  for (int rep = 0; rep < 4; ++rep) {
    const int e = rep * 256 + tid;
    const int h = e >> 6, i = e & 63;
    float acc = 0.f;
#pragma unroll 4
    for (int dd = 0; dd < DH; ++dd) acc += Wq[dd * DH + i] * kw_s[h * 64 + dd];
    wqkw_s[h * 66 + i] = acc;
  }
  if (tid < HNUM) {
    float acc = 0.f;
#pragma unroll 4
    for (int dd = 0; dd < DH; ++dd) acc += bq[dd] * kw_s[tid * 64 + dd];
    bqkw_s[tid] = acc;
  }
  __syncthreads();
  // ---- D: direct per-thread score dots ----
  if (tid < 128) {
    const int h = tid >> 3, b2 = tid & 7;
    const float* qrow = q + b2 * NFEAT + h * DH;
    const float* wrow = wqkw_s + h * 66;
    float acc = 0.f;
#pragma unroll
    for (int i4 = 0; i4 < 16; ++i4) {
      const float4 qv = *(const float4*)(qrow + i4 * 4);
      acc += qv.x * wrow[i4 * 4 + 0] + qv.y * wrow[i4 * 4 + 1] +
             qv.z * wrow[i4 * 4 + 2] + qv.w * wrow[i4 * 4 + 3];
    }
    scores[(((size_t)b1 * HNUM + h) * BDIM + b2) * LDIM + l] =
        (acc + bqkw_s[h]) * 0.125f;
  }
  // ---- E: weff row f = bl ----
  {
    const int f = bl;
    *(float4*)(worow + tid * 4) = *(const float4*)(Wo + (size_t)f * NFEAT + tid * 4);
    __syncthreads();
    const int g0 = tid * 4;
    const int hbase = (g0 >> 6) << 6;
    const int i0 = g0 & 63;
    float a0 = 0, a1 = 0, a2 = 0, a3 = 0;
#pragma unroll 4
    for (int d = 0; d < DH; ++d) {
      const float wod = worow[hbase + d];
      const float4 wv4 = *(const float4*)(Wv + d * DH + i0);
      a0 += wod * wv4.x; a1 += wod * wv4.y; a2 += wod * wv4.z; a3 += wod * wv4.w;
    }
    ushort4 pk;
    pk.x = f2bf(a0); pk.y = f2bf(a1); pk.z = f2bf(a2); pk.w = f2bf(a3);
    *(ushort4*)(Weff + (size_t)f * NFEAT + g0) = pk;
    red[tid] = worow[g0 + 0] * bv[i0 + 0] + worow[g0 + 1] * bv[i0 + 1] +
               worow[g0 + 2] * bv[i0 + 2] + worow[g0 + 3] * bv[i0 + 3];
    __syncthreads();
    for (int sft = 128; sft > 0; sft >>= 1) {
      if (tid < sft) red[tid] += red[tid + sft];
      __syncthreads();
    }
    if (tid == 0) beff[f] = bo[f] + red[0];
  }
}

// ---------------------------------------------------------------------------
// Kernel 2: FUSED pool + gemm.  256 blocks x 512 threads (1 block/CU, 8 waves).
// Block (b1, t-pair): owns 16 full K=1024 rows of A = one 16-row MFMA M-tile.
//  P1 softmax prologue (threads 0..127): scores row -> wlds[h*1032+b2*129+l]
//     (h-broadcasts land on banks +0/+8/+16/+24: conflict-free).
//  P2 stream kv ONCE (R6-proven 8-deep float4 batches; wave = 1KB coalesced),
//     accumulate 8 b2 x float4 in regs; write bf16 -> plds[16][pitch 1032]
//     (pitch 1032*2B => a-frag reads 2-way-free).
//  P3 gemm: wave w owns N-cols [w*128, w*128+128); a from plds, b straight
//     from L2-resident Weff (16B/lane); 2048 MFMA/block; direct out writes.
// No pooled HBM round-trip, no third dispatch.
// ---------------------------------------------------------------------------
__global__ __launch_bounds__(512) void pool_gemm_kernel(
    const float* __restrict__ kv, const float* __restrict__ scores,
    const unsigned short* __restrict__ Weff, const float* __restrict__ beff,
    float* __restrict__ out) {
  __shared__ float wlds[16 * 1032];             // 66 KB
  __shared__ unsigned short plds[16 * 1032];    // 33 KB
  const int blk = blockIdx.x;        // 256 = 8 b1 * 32 t-pairs
  const int b1 = blk >> 5;
  const int t0 = (blk & 31) * 2;
  const int tid = threadIdx.x;

  // ---- P1: softmax prologue (two-pass, register-light) ----
  if (tid < 128) {
    const int h = tid >> 3, b2 = tid & 7;
    const float* srow = scores + (((size_t)b1 * HNUM + h) * BDIM + b2) * LDIM;
    float m = -1e30f;
    for (int j = 0; j < 32; ++j) {
      const float4 s4 = *(const float4*)(srow + j * 4);
      m = fmaxf(m, fmaxf(fmaxf(s4.x, s4.y), fmaxf(s4.z, s4.w)));
    }
    float ssum = 0.f;
    float* wdst = wlds + h * 1032 + b2 * 129;
    for (int j = 0; j < 32; ++j) {
      const float4 s4 = *(const float4*)(srow + j * 4);
      const float e0 = expf(s4.x - m), e1 = expf(s4.y - m);
      const float e2 = expf(s4.z - m), e3 = expf(s4.w - m);
      wdst[j * 4 + 0] = e0; wdst[j * 4 + 1] = e1;
      wdst[j * 4 + 2] = e2; wdst[j * 4 + 3] = e3;
      ssum += e0 + e1 + e2 + e3;
    }
    const float inv = 1.f / ssum;
    for (int j = 0; j < 128; ++j) wdst[j] *= inv;
  }
  __syncthreads();

  // ---- P2: stream kv, accumulate, pooled tile -> LDS bf16 ----
  {
    const int tt = tid >> 8;              // 0/1 within t-pair
    const int f0 = (tid & 255) * 4;
    const int hh = f0 >> 6;               // head 0..15
    const float* kvb =
        kv + (((size_t)b1 * LDIM) * TDIM + (t0 + tt)) * NFEAT + f0;
    const float* wbase = wlds + hh * 1032;
    float4 acc[8];
#pragma unroll
    for (int b2 = 0; b2 < 8; ++b2) acc[b2] = make_float4(0.f, 0.f, 0.f, 0.f);
    for (int l0 = 0; l0 < LDIM; l0 += 8) {
      float4 v[8];
#pragma unroll
      for (int j = 0; j < 8; ++j)
        v[j] = *(const float4*)(kvb + (size_t)(l0 + j) * (TDIM * NFEAT));
#pragma unroll
      for (int j = 0; j < 8; ++j) {
#pragma unroll
        for (int b2 = 0; b2 < 8; ++b2) {
          const float w = wbase[b2 * 129 + l0 + j];
          acc[b2].x += w * v[j].x; acc[b2].y += w * v[j].y;
          acc[b2].z += w * v[j].z; acc[b2].w += w * v[j].w;
        }
      }
    }
#pragma unroll
    for (int b2 = 0; b2 < 8; ++b2) {
      ushort4 pk;
      pk.x = f2bf(acc[b2].x); pk.y = f2bf(acc[b2].y);
      pk.z = f2bf(acc[b2].z); pk.w = f2bf(acc[b2].w);
      *(ushort4*)(plds + (tt * 8 + b2) * 1032 + f0) = pk;
    }
  }
  __syncthreads();

  // ---- P3: gemm 16 rows x 1024 cols x K=1024 ----
  {
    const int wv = tid >> 6, lane = tid & 63;
    const int rl = lane & 15, ks = lane >> 4;
    const int nb = wv * 128;
    f32x4 gacc[8] = {};
    for (int k0 = 0; k0 < GK; k0 += 32) {
      const short8 a =
          *(const short8*)((const char*)plds + rl * 2064 + (k0 + ks * 8) * 2);
#pragma unroll
      for (int n = 0; n < 8; ++n) {
        const short8 b = *(const short8*)(Weff +
            (size_t)(nb + n * 16 + rl) * GK + k0 + ks * 8);
        gacc[n] = __builtin_amdgcn_mfma_f32_16x16x32_bf16(a, b, gacc[n], 0, 0, 0);
      }
    }
    const size_t row0 = (size_t)(b1 * 64 + t0) * 8 + ks * 4;
#pragma unroll
    for (int n = 0; n < 8; ++n) {
      const int col = nb + n * 16 + rl;
      const float bvv = beff[col];
#pragma unroll
      for (int j2 = 0; j2 < 4; ++j2)
        out[(row0 + j2) * GN + col] = gacc[n][j2] + bvv;
    }
  }
}

extern "C" void kernel_launch(void* const* d_in, const int* in_sizes, int n_in,
                              void* d_out, int out_size, void* d_ws, size_t ws_size,
                              hipStream_t stream) {
  const float* q  = (const float*)d_in[0];
  const float* kv = (const float*)d_in[1];
  const float* Wq = (const float*)d_in[2];
  const float* bq = (const float*)d_in[3];
  const float* Wk = (const float*)d_in[4];
  // d_in[5] = bk: dropped (constant shift per softmax row -> no effect)
  const float* Wv = (const float*)d_in[6];
  const float* bv = (const float*)d_in[7];
  const float* Wo = (const float*)d_in[8];
  const float* bo = (const float*)d_in[9];
  float* out = (float*)d_out;

  char* ws = (char*)d_ws;
  float*          scores = (float*)ws;                      // 512 KB  [b1][h][b2][l]
  float*          beff   = (float*)(ws + (1u << 20));       // 4 KB
  unsigned short* Weff   = (unsigned short*)(ws + (1u << 20) + (4u << 10));  // 2 MB

  mean_score_weff_kernel<<<BDIM * LDIM, 256, 0, stream>>>(
      kv, q, Wq, bq, Wk, Wo, Wv, bv, bo, scores, Weff, beff);
  pool_gemm_kernel<<<256, 512, 0, stream>>>(kv, scores, Weff, beff, out);
}

// Round 11
// 138.132 us; speedup vs baseline: 1.2860x; 1.2860x over previous
//
#include <hip/hip_runtime.h>
#include <hip/hip_bf16.h>

#define BDIM 8
#define LDIM 128
#define TDIM 64
#define NFEAT 1024
#define HNUM 16
#define DH 64

#define GM 4096
#define GN 1024
#define GK 1024

typedef __attribute__((ext_vector_type(8))) short short8;
typedef __attribute__((ext_vector_type(4))) float f32x4;

// round-to-nearest-even f32 -> bf16 bits
__device__ __forceinline__ unsigned short f2bf(float x) {
  union { float f; unsigned u; } v; v.f = x;
  unsigned r = v.u + 0x7fffu + ((v.u >> 16) & 1u);
  return (unsigned short)(r >> 16);
}

__device__ __forceinline__ void gload_lds16(const void* g, void* l) {
  __builtin_amdgcn_global_load_lds((const __attribute__((address_space(1))) void*)g,
                                   (__attribute__((address_space(3))) void*)l, 16, 0, 0);
}

// ---------------------------------------------------------------------------
// Kernel 1: per block bl=(b1,l):
//   A: km = mean_t kv[bl] (LDS only)
//   B: kw[h][dd]  = sum_d Wk[dd][d]*km[h*64+d]
//   C: wqkw[h][i] = sum_dd Wq[dd][i]*kw[h][dd]; bqkw[h] = sum_dd bq[dd]*kw[h][dd]
//   D: score[h,b2] direct per-thread dots  (worow load issued BEFORE D: overlap)
//   E: weff row f=bl; beff reduce via wave shfl (1 barrier, was 8)
// Scores layout: [b1][h][b2][l] (contiguous in l).
// ---------------------------------------------------------------------------
__global__ __launch_bounds__(256) void mean_score_weff_kernel(
    const float* __restrict__ kv, const float* __restrict__ q,
    const float* __restrict__ Wq, const float* __restrict__ bq,
    const float* __restrict__ Wk, const float* __restrict__ Wo,
    const float* __restrict__ Wv, const float* __restrict__ bv,
    const float* __restrict__ bo, float* __restrict__ scores,
    unsigned short* __restrict__ Weff, float* __restrict__ beff) {
  __shared__ float km_s[NFEAT];
  __shared__ float Wk_s[DH * 67];
  __shared__ float kw_s[HNUM * DH];
  __shared__ float wqkw_s[HNUM * 66];
  __shared__ float bqkw_s[HNUM];
  __shared__ float worow[NFEAT];
  __shared__ float red[4];
  const int bl = blockIdx.x;  // b1*128 + l
  const int tid = threadIdx.x;
  const int b1 = bl >> 7, l = bl & 127;

  // ---- A: mean over t of kv[bl, t, :] -> km_s ----
  {
    const float* src = kv + (size_t)bl * (TDIM * NFEAT) + tid * 4;
    float4 acc = make_float4(0.f, 0.f, 0.f, 0.f);
    for (int t0 = 0; t0 < TDIM; t0 += 8) {
      float4 v[8];
#pragma unroll
      for (int jj = 0; jj < 8; ++jj)
        v[jj] = *(const float4*)(src + (t0 + jj) * NFEAT);
#pragma unroll
      for (int jj = 0; jj < 8; ++jj) {
        acc.x += v[jj].x; acc.y += v[jj].y; acc.z += v[jj].z; acc.w += v[jj].w;
      }
    }
    const float s = 1.f / TDIM;
    *(float4*)(km_s + tid * 4) = make_float4(acc.x * s, acc.y * s, acc.z * s, acc.w * s);
  }
#pragma unroll
  for (int rep = 0; rep < 4; ++rep) {
    const int e4 = rep * 256 + tid;
    const int row = e4 >> 4, c4 = e4 & 15;
    const float4 v = *(const float4*)(Wk + row * DH + c4 * 4);
    float* dst = Wk_s + row * 67 + c4 * 4;
    dst[0] = v.x; dst[1] = v.y; dst[2] = v.z; dst[3] = v.w;
  }
  __syncthreads();
  // ---- B: kw ----
#pragma unroll
  for (int rep = 0; rep < 4; ++rep) {
    const int e = rep * 256 + tid;
    const int h = e >> 6, dd = e & 63;
    float acc = 0.f;
#pragma unroll 4
    for (int d = 0; d < DH; ++d) acc += Wk_s[dd * 67 + d] * km_s[h * 64 + d];
    kw_s[h * 64 + dd] = acc;
  }
  __syncthreads();
  // ---- C: wqkw + bqkw ----
#pragma unroll
  for (int rep = 0; rep < 4; ++rep) {
    const int e = rep * 256 + tid;
    const int h = e >> 6, i = e & 63;
    float acc = 0.f;
#pragma unroll 4
    for (int dd = 0; dd < DH; ++dd) acc += Wq[dd * DH + i] * kw_s[h * 64 + dd];
    wqkw_s[h * 66 + i] = acc;
  }
  if (tid < HNUM) {
    float acc = 0.f;
#pragma unroll 4
    for (int dd = 0; dd < DH; ++dd) acc += bq[dd] * kw_s[tid * 64 + dd];
    bqkw_s[tid] = acc;
  }
  __syncthreads();
  // ---- worow load issued BEFORE D: threads 128-255 (idle in D) fetch early,
  //      and D-threads' load latency hides under the 64-FMA dot ----
  *(float4*)(worow + tid * 4) = *(const float4*)(Wo + (size_t)bl * NFEAT + tid * 4);
  // ---- D: direct per-thread score dots ----
  if (tid < 128) {
    const int h = tid >> 3, b2 = tid & 7;
    const float* qrow = q + b2 * NFEAT + h * DH;
    const float* wrow = wqkw_s + h * 66;
    float acc = 0.f;
#pragma unroll
    for (int i4 = 0; i4 < 16; ++i4) {
      const float4 qv = *(const float4*)(qrow + i4 * 4);
      acc += qv.x * wrow[i4 * 4 + 0] + qv.y * wrow[i4 * 4 + 1] +
             qv.z * wrow[i4 * 4 + 2] + qv.w * wrow[i4 * 4 + 3];
    }
    scores[(((size_t)b1 * HNUM + h) * BDIM + b2) * LDIM + l] =
        (acc + bqkw_s[h]) * 0.125f;
  }
  __syncthreads();   // worow visible to all; D done
  // ---- E: weff row f = bl ----
  {
    const int g0 = tid * 4;
    const int hbase = (g0 >> 6) << 6;
    const int i0 = g0 & 63;
    float a0 = 0, a1 = 0, a2 = 0, a3 = 0;
#pragma unroll 4
    for (int d = 0; d < DH; ++d) {
      const float wod = worow[hbase + d];
      const float4 wv4 = *(const float4*)(Wv + d * DH + i0);
      a0 += wod * wv4.x; a1 += wod * wv4.y; a2 += wod * wv4.z; a3 += wod * wv4.w;
    }
    ushort4 pk;
    pk.x = f2bf(a0); pk.y = f2bf(a1); pk.z = f2bf(a2); pk.w = f2bf(a3);
    *(ushort4*)(Weff + (size_t)bl * NFEAT + g0) = pk;
    // beff partial: wave shfl reduce (1 barrier instead of 8)
    float r = worow[g0 + 0] * bv[i0 + 0] + worow[g0 + 1] * bv[i0 + 1] +
              worow[g0 + 2] * bv[i0 + 2] + worow[g0 + 3] * bv[i0 + 3];
#pragma unroll
    for (int s = 1; s < 64; s <<= 1) r += __shfl_xor(r, s, 64);
    if ((tid & 63) == 0) red[tid >> 6] = r;
    __syncthreads();
    if (tid == 0) beff[bl] = bo[bl] + red[0] + red[1] + red[2] + red[3];
  }
}

// ---------------------------------------------------------------------------
// Kernel 2: pool with softmax prologue (R9-proven body, verbatim).
// ---------------------------------------------------------------------------
#define HSTRIDE 1032
__global__ __launch_bounds__(64) void pool_kernel(
    const float* __restrict__ kv, const float* __restrict__ scores,
    unsigned short* __restrict__ pooled) {
  __shared__ float wlds[4 * HSTRIDE];
  const int b1 = blockIdx.x;
  const int t = blockIdx.y;
  const int ftile = blockIdx.z;
  const int tid = threadIdx.x;
  // ---- softmax prologue ----
  {
    const int row = tid & 31;           // hloc*8 + b2
    const int half = tid >> 5;
    const int hloc = row >> 3, b2 = row & 7;
    const float* srow = scores +
        (((size_t)b1 * HNUM + ftile * 4 + hloc) * BDIM + b2) * LDIM + half * 64;
    float4 sv[16];
#pragma unroll
    for (int j = 0; j < 16; ++j) sv[j] = *(const float4*)(srow + j * 4);
    float m = -1e30f;
#pragma unroll
    for (int j = 0; j < 16; ++j)
      m = fmaxf(m, fmaxf(fmaxf(sv[j].x, sv[j].y), fmaxf(sv[j].z, sv[j].w)));
    m = fmaxf(m, __shfl_xor(m, 32, 64));
    float ssum = 0.f;
#pragma unroll
    for (int j = 0; j < 16; ++j) {
      sv[j].x = expf(sv[j].x - m); sv[j].y = expf(sv[j].y - m);
      sv[j].z = expf(sv[j].z - m); sv[j].w = expf(sv[j].w - m);
      ssum += sv[j].x + sv[j].y + sv[j].z + sv[j].w;
    }
    ssum += __shfl_xor(ssum, 32, 64);
    const float inv = 1.f / ssum;
    float* wdst = wlds + hloc * HSTRIDE + b2 * LDIM + half * 64;
#pragma unroll
    for (int j = 0; j < 16; ++j) {
      float4 w4 = make_float4(sv[j].x * inv, sv[j].y * inv, sv[j].z * inv, sv[j].w * inv);
      *(float4*)(wdst + j * 4) = w4;
    }
  }
  __syncthreads();
  // ---- main loop ----
  const int f = ftile * 256 + tid * 4;
  const int hh = tid >> 4;
  const float* kvbase = kv + ((size_t)b1 * LDIM) * (TDIM * NFEAT) + t * NFEAT + f;
  float4 acc[8];
#pragma unroll
  for (int b2 = 0; b2 < 8; ++b2) acc[b2] = make_float4(0.f, 0.f, 0.f, 0.f);
  const float* wbase = wlds + hh * HSTRIDE;
  for (int l0 = 0; l0 < LDIM; l0 += 8) {
    float4 v[8];
#pragma unroll
    for (int j = 0; j < 8; ++j)
      v[j] = *(const float4*)(kvbase + (size_t)(l0 + j) * (TDIM * NFEAT));
#pragma unroll
    for (int j = 0; j < 8; ++j) {
#pragma unroll
      for (int b2 = 0; b2 < 8; ++b2) {
        const float w = wbase[b2 * LDIM + l0 + j];
        acc[b2].x += w * v[j].x; acc[b2].y += w * v[j].y;
        acc[b2].z += w * v[j].z; acc[b2].w += w * v[j].w;
      }
    }
  }
  unsigned short* obase = pooled + ((size_t)(b1 * TDIM + t) * BDIM) * NFEAT + f;
#pragma unroll
  for (int b2 = 0; b2 < 8; ++b2) {
    ushort4 pk;
    pk.x = f2bf(acc[b2].x); pk.y = f2bf(acc[b2].y);
    pk.z = f2bf(acc[b2].z); pk.w = f2bf(acc[b2].w);
    *(ushort4*)(obase + b2 * NFEAT) = pk;
  }
}

// ---------------------------------------------------------------------------
// Kernel 3: bf16 MFMA GEMM (R3/R6/R9-proven body, verbatim).
// ---------------------------------------------------------------------------
__global__ __launch_bounds__(256) void mfma_gemm(const unsigned short* __restrict__ A,
                                                 const unsigned short* __restrict__ W,
                                                 const float* __restrict__ beff,
                                                 float* __restrict__ out) {
  __shared__ unsigned short As[2][128 * 32];
  __shared__ unsigned short Bs[2][64 * 32];
  const int tid = threadIdx.x;
  const int w = tid >> 6, l = tid & 63;
  const int mBase = blockIdx.y * 128, nBase = blockIdx.x * 64;
  const int wr = w >> 1, wc = w & 1;

  int arow[2], acol[2];
#pragma unroll
  for (int j = 0; j < 2; ++j) {
    const int cid = j * 256 + tid;
    const int r = cid >> 2, c = cid & 3;
    arow[j] = r;
    acol[j] = (c ^ ((r >> 1) & 3)) * 8;
  }
  const int brow = tid >> 2;
  const int bcol = ((tid & 3) ^ ((brow >> 1) & 3)) * 8;

  const int rl = l & 15, ks = l >> 4;
  const int fsel = (ks ^ ((rl >> 1) & 3)) * 16;

  f32x4 acc[4][2] = {};

#pragma unroll
  for (int j = 0; j < 2; ++j)
    gload_lds16(A + (size_t)(mBase + arow[j]) * GK + acol[j],
                (char*)As[0] + (j * 256 + tid) * 16);
  gload_lds16(W + (size_t)(nBase + brow) * GK + bcol, (char*)Bs[0] + tid * 16);
  __syncthreads();

  int cur = 0;
  for (int t = 0; t < GK / 32; ++t) {
    if (t + 1 < GK / 32) {
      const int k0 = (t + 1) * 32;
#pragma unroll
      for (int j = 0; j < 2; ++j)
        gload_lds16(A + (size_t)(mBase + arow[j]) * GK + k0 + acol[j],
                    (char*)As[cur ^ 1] + (j * 256 + tid) * 16);
      gload_lds16(W + (size_t)(nBase + brow) * GK + k0 + bcol,
                  (char*)Bs[cur ^ 1] + tid * 16);
    }
    short8 a[4], b[2];
#pragma unroll
    for (int m = 0; m < 4; ++m)
      a[m] = *(const short8*)((const char*)As[cur] + (wr * 64 + m * 16 + rl) * 64 + fsel);
#pragma unroll
    for (int n = 0; n < 2; ++n)
      b[n] = *(const short8*)((const char*)Bs[cur] + (wc * 32 + n * 16 + rl) * 64 + fsel);
#pragma unroll
    for (int m = 0; m < 4; ++m)
#pragma unroll
      for (int n = 0; n < 2; ++n)
        acc[m][n] = __builtin_amdgcn_mfma_f32_16x16x32_bf16(a[m], b[n], acc[m][n], 0, 0, 0);
    __syncthreads();
    cur ^= 1;
  }

#pragma unroll
  for (int n = 0; n < 2; ++n) {
    const int col = nBase + wc * 32 + n * 16 + rl;
    const float bv = beff[col];
#pragma unroll
    for (int m = 0; m < 4; ++m) {
      const int row0 = mBase + wr * 64 + m * 16 + ks * 4;
#pragma unroll
      for (int j2 = 0; j2 < 4; ++j2)
        out[(size_t)(row0 + j2) * GN + col] = acc[m][n][j2] + bv;
    }
  }
}

extern "C" void kernel_launch(void* const* d_in, const int* in_sizes, int n_in,
                              void* d_out, int out_size, void* d_ws, size_t ws_size,
                              hipStream_t stream) {
  const float* q  = (const float*)d_in[0];
  const float* kv = (const float*)d_in[1];
  const float* Wq = (const float*)d_in[2];
  const float* bq = (const float*)d_in[3];
  const float* Wk = (const float*)d_in[4];
  // d_in[5] = bk: dropped (constant shift per softmax row -> no effect)
  const float* Wv = (const float*)d_in[6];
  const float* bv = (const float*)d_in[7];
  const float* Wo = (const float*)d_in[8];
  const float* bo = (const float*)d_in[9];
  float* out = (float*)d_out;

  char* ws = (char*)d_ws;
  float*          scores = (float*)ws;                      // 512 KB  [b1][h][b2][l]
  float*          beff   = (float*)(ws + (1u << 20));       // 4 KB
  unsigned short* Weff   = (unsigned short*)(ws + (1u << 20) + (4u << 10));  // 2 MB
  unsigned short* pooled = (unsigned short*)(ws + (4u << 20));               // 8 MB

  mean_score_weff_kernel<<<BDIM * LDIM, 256, 0, stream>>>(
      kv, q, Wq, bq, Wk, Wo, Wv, bv, bo, scores, Weff, beff);
  pool_kernel<<<dim3(BDIM, TDIM, 4), 64, 0, stream>>>(kv, scores, pooled);
  mfma_gemm<<<dim3(GN / 64, GM / 128), 256, 0, stream>>>(pooled, Weff, beff, out);
}

// Round 12
// 135.466 us; speedup vs baseline: 1.3113x; 1.0197x over previous
//
#include <hip/hip_runtime.h>
#include <hip/hip_bf16.h>

#define BDIM 8
#define LDIM 128
#define TDIM 64
#define NFEAT 1024
#define HNUM 16
#define DH 64

#define GM 4096
#define GN 1024
#define GK 1024

typedef __attribute__((ext_vector_type(8))) short short8;
typedef __attribute__((ext_vector_type(4))) float f32x4;

// round-to-nearest-even f32 -> bf16 bits
__device__ __forceinline__ unsigned short f2bf(float x) {
  union { float f; unsigned u; } v; v.f = x;
  unsigned r = v.u + 0x7fffu + ((v.u >> 16) & 1u);
  return (unsigned short)(r >> 16);
}

__device__ __forceinline__ void gload_lds16(const void* g, void* l) {
  __builtin_amdgcn_global_load_lds((const __attribute__((address_space(1))) void*)g,
                                   (__attribute__((address_space(3))) void*)l, 16, 0, 0);
}

// ---------------------------------------------------------------------------
// Kernel 1 (R11-proven body, verbatim): per block bl=(b1,l):
//   A: km = mean_t kv[bl] (LDS only)
//   B: kw[h][dd]  = sum_d Wk[dd][d]*km[h*64+d]
//   C: wqkw[h][i] = sum_dd Wq[dd][i]*kw[h][dd]; bqkw[h] = sum_dd bq[dd]*kw[h][dd]
//   D: score[h,b2] direct per-thread dots  (worow load issued BEFORE D)
//   E: weff row f=bl; beff reduce via wave shfl
// Scores layout: [b1][h][b2][l] (contiguous in l).
// ---------------------------------------------------------------------------
__global__ __launch_bounds__(256) void mean_score_weff_kernel(
    const float* __restrict__ kv, const float* __restrict__ q,
    const float* __restrict__ Wq, const float* __restrict__ bq,
    const float* __restrict__ Wk, const float* __restrict__ Wo,
    const float* __restrict__ Wv, const float* __restrict__ bv,
    const float* __restrict__ bo, float* __restrict__ scores,
    unsigned short* __restrict__ Weff, float* __restrict__ beff) {
  __shared__ float km_s[NFEAT];
  __shared__ float Wk_s[DH * 67];
  __shared__ float kw_s[HNUM * DH];
  __shared__ float wqkw_s[HNUM * 66];
  __shared__ float bqkw_s[HNUM];
  __shared__ float worow[NFEAT];
  __shared__ float red[4];
  const int bl = blockIdx.x;  // b1*128 + l
  const int tid = threadIdx.x;
  const int b1 = bl >> 7, l = bl & 127;

  // ---- A: mean over t of kv[bl, t, :] -> km_s ----
  {
    const float* src = kv + (size_t)bl * (TDIM * NFEAT) + tid * 4;
    float4 acc = make_float4(0.f, 0.f, 0.f, 0.f);
    for (int t0 = 0; t0 < TDIM; t0 += 8) {
      float4 v[8];
#pragma unroll
      for (int jj = 0; jj < 8; ++jj)
        v[jj] = *(const float4*)(src + (t0 + jj) * NFEAT);
#pragma unroll
      for (int jj = 0; jj < 8; ++jj) {
        acc.x += v[jj].x; acc.y += v[jj].y; acc.z += v[jj].z; acc.w += v[jj].w;
      }
    }
    const float s = 1.f / TDIM;
    *(float4*)(km_s + tid * 4) = make_float4(acc.x * s, acc.y * s, acc.z * s, acc.w * s);
  }
#pragma unroll
  for (int rep = 0; rep < 4; ++rep) {
    const int e4 = rep * 256 + tid;
    const int row = e4 >> 4, c4 = e4 & 15;
    const float4 v = *(const float4*)(Wk + row * DH + c4 * 4);
    float* dst = Wk_s + row * 67 + c4 * 4;
    dst[0] = v.x; dst[1] = v.y; dst[2] = v.z; dst[3] = v.w;
  }
  __syncthreads();
  // ---- B: kw ----
#pragma unroll
  for (int rep = 0; rep < 4; ++rep) {
    const int e = rep * 256 + tid;
    const int h = e >> 6, dd = e & 63;
    float acc = 0.f;
#pragma unroll 4
    for (int d = 0; d < DH; ++d) acc += Wk_s[dd * 67 + d] * km_s[h * 64 + d];
    kw_s[h * 64 + dd] = acc;
  }
  __syncthreads();
  // ---- C: wqkw + bqkw ----
#pragma unroll
  for (int rep = 0; rep < 4; ++rep) {
    const int e = rep * 256 + tid;
    const int h = e >> 6, i = e & 63;
    float acc = 0.f;
#pragma unroll 4
    for (int dd = 0; dd < DH; ++dd) acc += Wq[dd * DH + i] * kw_s[h * 64 + dd];
    wqkw_s[h * 66 + i] = acc;
  }
  if (tid < HNUM) {
    float acc = 0.f;
#pragma unroll 4
    for (int dd = 0; dd < DH; ++dd) acc += bq[dd] * kw_s[tid * 64 + dd];
    bqkw_s[tid] = acc;
  }
  __syncthreads();
  // ---- worow load issued BEFORE D (overlap) ----
  *(float4*)(worow + tid * 4) = *(const float4*)(Wo + (size_t)bl * NFEAT + tid * 4);
  // ---- D: direct per-thread score dots ----
  if (tid < 128) {
    const int h = tid >> 3, b2 = tid & 7;
    const float* qrow = q + b2 * NFEAT + h * DH;
    const float* wrow = wqkw_s + h * 66;
    float acc = 0.f;
#pragma unroll
    for (int i4 = 0; i4 < 16; ++i4) {
      const float4 qv = *(const float4*)(qrow + i4 * 4);
      acc += qv.x * wrow[i4 * 4 + 0] + qv.y * wrow[i4 * 4 + 1] +
             qv.z * wrow[i4 * 4 + 2] + qv.w * wrow[i4 * 4 + 3];
    }
    scores[(((size_t)b1 * HNUM + h) * BDIM + b2) * LDIM + l] =
        (acc + bqkw_s[h]) * 0.125f;
  }
  __syncthreads();
  // ---- E: weff row f = bl ----
  {
    const int g0 = tid * 4;
    const int hbase = (g0 >> 6) << 6;
    const int i0 = g0 & 63;
    float a0 = 0, a1 = 0, a2 = 0, a3 = 0;
#pragma unroll 4
    for (int d = 0; d < DH; ++d) {
      const float wod = worow[hbase + d];
      const float4 wv4 = *(const float4*)(Wv + d * DH + i0);
      a0 += wod * wv4.x; a1 += wod * wv4.y; a2 += wod * wv4.z; a3 += wod * wv4.w;
    }
    ushort4 pk;
    pk.x = f2bf(a0); pk.y = f2bf(a1); pk.z = f2bf(a2); pk.w = f2bf(a3);
    *(ushort4*)(Weff + (size_t)bl * NFEAT + g0) = pk;
    float r = worow[g0 + 0] * bv[i0 + 0] + worow[g0 + 1] * bv[i0 + 1] +
              worow[g0 + 2] * bv[i0 + 2] + worow[g0 + 3] * bv[i0 + 3];
#pragma unroll
    for (int s = 1; s < 64; s <<= 1) r += __shfl_xor(r, s, 64);
    if ((tid & 63) == 0) red[tid >> 6] = r;
    __syncthreads();
    if (tid == 0) beff[bl] = bo[bl] + red[0] + red[1] + red[2] + red[3];
  }
}

// ---------------------------------------------------------------------------
// Kernel 2: pool with softmax prologue (R9/R11-proven body, verbatim).
// ---------------------------------------------------------------------------
#define HSTRIDE 1032
__global__ __launch_bounds__(64) void pool_kernel(
    const float* __restrict__ kv, const float* __restrict__ scores,
    unsigned short* __restrict__ pooled) {
  __shared__ float wlds[4 * HSTRIDE];
  const int b1 = blockIdx.x;
  const int t = blockIdx.y;
  const int ftile = blockIdx.z;
  const int tid = threadIdx.x;
  {
    const int row = tid & 31;
    const int half = tid >> 5;
    const int hloc = row >> 3, b2 = row & 7;
    const float* srow = scores +
        (((size_t)b1 * HNUM + ftile * 4 + hloc) * BDIM + b2) * LDIM + half * 64;
    float4 sv[16];
#pragma unroll
    for (int j = 0; j < 16; ++j) sv[j] = *(const float4*)(srow + j * 4);
    float m = -1e30f;
#pragma unroll
    for (int j = 0; j < 16; ++j)
      m = fmaxf(m, fmaxf(fmaxf(sv[j].x, sv[j].y), fmaxf(sv[j].z, sv[j].w)));
    m = fmaxf(m, __shfl_xor(m, 32, 64));
    float ssum = 0.f;
#pragma unroll
    for (int j = 0; j < 16; ++j) {
      sv[j].x = expf(sv[j].x - m); sv[j].y = expf(sv[j].y - m);
      sv[j].z = expf(sv[j].z - m); sv[j].w = expf(sv[j].w - m);
      ssum += sv[j].x + sv[j].y + sv[j].z + sv[j].w;
    }
    ssum += __shfl_xor(ssum, 32, 64);
    const float inv = 1.f / ssum;
    float* wdst = wlds + hloc * HSTRIDE + b2 * LDIM + half * 64;
#pragma unroll
    for (int j = 0; j < 16; ++j) {
      float4 w4 = make_float4(sv[j].x * inv, sv[j].y * inv, sv[j].z * inv, sv[j].w * inv);
      *(float4*)(wdst + j * 4) = w4;
    }
  }
  __syncthreads();
  const int f = ftile * 256 + tid * 4;
  const int hh = tid >> 4;
  const float* kvbase = kv + ((size_t)b1 * LDIM) * (TDIM * NFEAT) + t * NFEAT + f;
  float4 acc[8];
#pragma unroll
  for (int b2 = 0; b2 < 8; ++b2) acc[b2] = make_float4(0.f, 0.f, 0.f, 0.f);
  const float* wbase = wlds + hh * HSTRIDE;
  for (int l0 = 0; l0 < LDIM; l0 += 8) {
    float4 v[8];
#pragma unroll
    for (int j = 0; j < 8; ++j)
      v[j] = *(const float4*)(kvbase + (size_t)(l0 + j) * (TDIM * NFEAT));
#pragma unroll
    for (int j = 0; j < 8; ++j) {
#pragma unroll
      for (int b2 = 0; b2 < 8; ++b2) {
        const float w = wbase[b2 * LDIM + l0 + j];
        acc[b2].x += w * v[j].x; acc[b2].y += w * v[j].y;
        acc[b2].z += w * v[j].z; acc[b2].w += w * v[j].w;
      }
    }
  }
  unsigned short* obase = pooled + ((size_t)(b1 * TDIM + t) * BDIM) * NFEAT + f;
#pragma unroll
  for (int b2 = 0; b2 < 8; ++b2) {
    ushort4 pk;
    pk.x = f2bf(acc[b2].x); pk.y = f2bf(acc[b2].y);
    pk.z = f2bf(acc[b2].z); pk.w = f2bf(acc[b2].w);
    *(ushort4*)(obase + b2 * NFEAT) = pk;
  }
}

// ---------------------------------------------------------------------------
// Kernel 3: bf16 MFMA GEMM, BK=64 (halved barrier count vs proven BK=32).
// 128x64 tile, 512 blocks = 2/CU, LDS 48 KB double-buffered.
// Swizzle: row = 8 x 16B chunks; store chunk c at c^(r&7); fragment read
// phys = (kk*4+ks)^(rl&7) -> 8 lanes per 4-bank group = 2-way (free, m136).
// Single barrier per K-step, stage-ahead (proven schedule).
// ---------------------------------------------------------------------------
__global__ __launch_bounds__(256) void mfma_gemm(const unsigned short* __restrict__ A,
                                                 const unsigned short* __restrict__ W,
                                                 const float* __restrict__ beff,
                                                 float* __restrict__ out) {
  __shared__ unsigned short As[2][128 * 64];  // 16 KB x2
  __shared__ unsigned short Bs[2][64 * 64];   // 8 KB x2
  const int tid = threadIdx.x;
  const int w = tid >> 6, l = tid & 63;
  const int mBase = blockIdx.y * 128, nBase = blockIdx.x * 64;
  const int wr = w >> 1, wc = w & 1;

  // A staging: 1024 chunks of 16B, 4/thread.  B: 512 chunks, 2/thread.
  int arow[4], acol[4];
#pragma unroll
  for (int j = 0; j < 4; ++j) {
    const int cid = j * 256 + tid;
    const int r = cid >> 3, p = cid & 7;
    arow[j] = r;
    acol[j] = (p ^ (r & 7)) * 8;   // logical k-element offset for this chunk
  }
  int brow[2], bcol[2];
#pragma unroll
  for (int j = 0; j < 2; ++j) {
    const int cid = j * 256 + tid;
    const int r = cid >> 3, p = cid & 7;
    brow[j] = r;
    bcol[j] = (p ^ (r & 7)) * 8;
  }

  const int rl = l & 15, ks = l >> 4;
  // swizzled byte offset within a 128B row, per kk half
  const int fsel0 = (((0 * 4) + ks) ^ (rl & 7)) * 16;
  const int fsel1 = (((1 * 4) + ks) ^ (rl & 7)) * 16;

  f32x4 acc[4][2] = {};

  // prologue: stage k-tile 0 into buffer 0
#pragma unroll
  for (int j = 0; j < 4; ++j)
    gload_lds16(A + (size_t)(mBase + arow[j]) * GK + acol[j],
                (char*)As[0] + (j * 256 + tid) * 16);
#pragma unroll
  for (int j = 0; j < 2; ++j)
    gload_lds16(W + (size_t)(nBase + brow[j]) * GK + bcol[j],
                (char*)Bs[0] + (j * 256 + tid) * 16);
  __syncthreads();

  int cur = 0;
  for (int t = 0; t < GK / 64; ++t) {
    if (t + 1 < GK / 64) {
      const int k0 = (t + 1) * 64;
#pragma unroll
      for (int j = 0; j < 4; ++j)
        gload_lds16(A + (size_t)(mBase + arow[j]) * GK + k0 + acol[j],
                    (char*)As[cur ^ 1] + (j * 256 + tid) * 16);
#pragma unroll
      for (int j = 0; j < 2; ++j)
        gload_lds16(W + (size_t)(nBase + brow[j]) * GK + k0 + bcol[j],
                    (char*)Bs[cur ^ 1] + (j * 256 + tid) * 16);
    }
#pragma unroll
    for (int kk = 0; kk < 2; ++kk) {
      const int fsel = kk ? fsel1 : fsel0;
      short8 a[4], b[2];
#pragma unroll
      for (int m = 0; m < 4; ++m)
        a[m] = *(const short8*)((const char*)As[cur] +
                                (wr * 64 + m * 16 + rl) * 128 + fsel);
#pragma unroll
      for (int n = 0; n < 2; ++n)
        b[n] = *(const short8*)((const char*)Bs[cur] +
                                (wc * 32 + n * 16 + rl) * 128 + fsel);
#pragma unroll
      for (int m = 0; m < 4; ++m)
#pragma unroll
        for (int n = 0; n < 2; ++n)
          acc[m][n] = __builtin_amdgcn_mfma_f32_16x16x32_bf16(a[m], b[n], acc[m][n], 0, 0, 0);
    }
    __syncthreads();  // drains vmcnt(0): next buffer staged; cur reads done
    cur ^= 1;
  }

  // epilogue: C/D layout col=lane&15, row=(lane>>4)*4+reg
#pragma unroll
  for (int n = 0; n < 2; ++n) {
    const int col = nBase + wc * 32 + n * 16 + rl;
    const float bv = beff[col];
#pragma unroll
    for (int m = 0; m < 4; ++m) {
      const int row0 = mBase + wr * 64 + m * 16 + ks * 4;
#pragma unroll
      for (int j2 = 0; j2 < 4; ++j2)
        out[(size_t)(row0 + j2) * GN + col] = acc[m][n][j2] + bv;
    }
  }
}

extern "C" void kernel_launch(void* const* d_in, const int* in_sizes, int n_in,
                              void* d_out, int out_size, void* d_ws, size_t ws_size,
                              hipStream_t stream) {
  const float* q  = (const float*)d_in[0];
  const float* kv = (const float*)d_in[1];
  const float* Wq = (const float*)d_in[2];
  const float* bq = (const float*)d_in[3];
  const float* Wk = (const float*)d_in[4];
  // d_in[5] = bk: dropped (constant shift per softmax row -> no effect)
  const float* Wv = (const float*)d_in[6];
  const float* bv = (const float*)d_in[7];
  const float* Wo = (const float*)d_in[8];
  const float* bo = (const float*)d_in[9];
  float* out = (float*)d_out;

  char* ws = (char*)d_ws;
  float*          scores = (float*)ws;                      // 512 KB  [b1][h][b2][l]
  float*          beff   = (float*)(ws + (1u << 20));       // 4 KB
  unsigned short* Weff   = (unsigned short*)(ws + (1u << 20) + (4u << 10));  // 2 MB
  unsigned short* pooled = (unsigned short*)(ws + (4u << 20));               // 8 MB

  mean_score_weff_kernel<<<BDIM * LDIM, 256, 0, stream>>>(
      kv, q, Wq, bq, Wk, Wo, Wv, bv, bo, scores, Weff, beff);
  pool_kernel<<<dim3(BDIM, TDIM, 4), 64, 0, stream>>>(kv, scores, pooled);
  mfma_gemm<<<dim3(GN / 64, GM / 128), 256, 0, stream>>>(pooled, Weff, beff, out);
}